// Round 3
// baseline (1828.592 us; speedup 1.0000x reference)
//
#include <hip/hip_runtime.h>
#include <math.h>

// XFADS: N=32, T=1024, D_OBS=128, D_Z=64, D_U=8, H_ENC=256, H_BW=128, H_DYN=256, D_A=128
#define T_LEN 1024
#define NB 32

#define REP16(X) X(0) X(1) X(2) X(3) X(4) X(5) X(6) X(7) X(8) X(9) X(10) X(11) X(12) X(13) X(14) X(15)

__device__ __forceinline__ float softplus_f(float x) {
    return fmaxf(x, 0.f) + log1pf(expf(-fabsf(x)));
}

// fast tanh: 1 - 2/(1+exp2(2*log2e*x)); exp2/rcp are 1-ulp HW ops.
__device__ __forceinline__ float fast_tanh(float x) {
    float e = __builtin_amdgcn_exp2f(x * 2.88539008177792681472f);
    float r = __builtin_amdgcn_rcpf(1.f + e);
    return 1.f - 2.f * r;
}

// raw barrier: drain LDS ops only; global prefetches stay in flight (T4 pattern)
__device__ __forceinline__ void bar_sync() {
    asm volatile("s_waitcnt lgkmcnt(0)" ::: "memory");
    __builtin_amdgcn_s_barrier();
    asm volatile("" ::: "memory");
}

// -------------------------------------------------------------------------
// K1: encoder  h = tanh(y@W1+b1); a = h@W2+b2;
//     apre[t][n][:] = a@bw_wa + bw_b
//     preU[t][n][:] = u@dyn_w1[64:72] + dyn_b1
// -------------------------------------------------------------------------
__global__ __launch_bounds__(256) void k_encoder(
    const float* __restrict__ y, const float* __restrict__ u,
    const float* __restrict__ w1, const float* __restrict__ b1,
    const float* __restrict__ w2, const float* __restrict__ b2,
    const float* __restrict__ wa, const float* __restrict__ bb,
    const float* __restrict__ dynw1, const float* __restrict__ dynb1,
    float* __restrict__ apre, float* __restrict__ preU)
{
    __shared__ float ly[8][128];
    __shared__ float lh[8][256];
    __shared__ float la[8][128];
    __shared__ float lu[8][8];
    const int tid = threadIdx.x;
    const int row0 = blockIdx.x * 8;

    ((float4*)&ly[0][0])[tid] = ((const float4*)(y + (size_t)row0 * 128))[tid];
    if (tid < 16)
        ((float4*)&lu[0][0])[tid] = ((const float4*)(u + (size_t)row0 * 8))[tid];
    __syncthreads();

    {
        float acc[8] = {0,0,0,0,0,0,0,0};
        for (int i = 0; i < 128; i += 4) {
            float w0 = w1[(i+0)*256 + tid];
            float w1v = w1[(i+1)*256 + tid];
            float w2v = w1[(i+2)*256 + tid];
            float w3 = w1[(i+3)*256 + tid];
            #pragma unroll
            for (int r = 0; r < 8; ++r) {
                float4 yv = *(const float4*)&ly[r][i];
                acc[r] += yv.x*w0 + yv.y*w1v + yv.z*w2v + yv.w*w3;
            }
        }
        float bias = b1[tid];
        #pragma unroll
        for (int r = 0; r < 8; ++r) lh[r][tid] = fast_tanh(acc[r] + bias);
    }
    __syncthreads();

    {
        const int d = tid & 127, rh = tid >> 7;
        float acc[4] = {0,0,0,0};
        for (int i = 0; i < 256; i += 4) {
            float w0 = w2[(i+0)*128 + d];
            float w1v = w2[(i+1)*128 + d];
            float w2v = w2[(i+2)*128 + d];
            float w3 = w2[(i+3)*128 + d];
            #pragma unroll
            for (int q = 0; q < 4; ++q) {
                float4 hv = *(const float4*)&lh[rh*4+q][i];
                acc[q] += hv.x*w0 + hv.y*w1v + hv.z*w2v + hv.w*w3;
            }
        }
        float bias = b2[d];
        #pragma unroll
        for (int q = 0; q < 4; ++q) la[rh*4+q][d] = acc[q] + bias;
    }
    __syncthreads();

    {
        const int j = tid & 127, rh = tid >> 7;
        float acc[4] = {0,0,0,0};
        for (int i = 0; i < 128; i += 4) {
            float w0 = wa[(i+0)*128 + j];
            float w1v = wa[(i+1)*128 + j];
            float w2v = wa[(i+2)*128 + j];
            float w3 = wa[(i+3)*128 + j];
            #pragma unroll
            for (int q = 0; q < 4; ++q) {
                float4 av = *(const float4*)&la[rh*4+q][i];
                acc[q] += av.x*w0 + av.y*w1v + av.z*w2v + av.w*w3;
            }
        }
        float bias = bb[j];
        #pragma unroll
        for (int q = 0; q < 4; ++q) {
            int rn = row0 + rh*4 + q;
            int n = rn >> 10, t = rn & 1023;
            apre[((size_t)t*NB + n)*128 + j] = acc[q] + bias;
        }
    }

    {
        float wu[8];
        #pragma unroll
        for (int c = 0; c < 8; ++c) wu[c] = dynw1[(64 + c)*256 + tid];
        float bias = dynb1[tid];
        #pragma unroll
        for (int r = 0; r < 8; ++r) {
            float acc = bias;
            #pragma unroll
            for (int c = 0; c < 8; ++c) acc += lu[r][c] * wu[c];
            int rn = row0 + r;
            int n = rn >> 10, t = rn & 1023;
            preU[((size_t)t*NB + n)*256 + tid] = acc;
        }
    }
}

// -------------------------------------------------------------------------
// K2: backward RNN scan. 512 threads = 2 batch groups of 256; grid NB/2.
// Thread (j = t256>>1, p = t256&1): 64-MAC partial, shfl_xor(1) reduce.
// Weights in 16 NAMED float4 registers (no alloca -> no scratch demotion).
// -------------------------------------------------------------------------
__global__ __launch_bounds__(512, 2) void k_bwscan(
    const float* __restrict__ apre, const float* __restrict__ wh,
    float* __restrict__ hcell)
{
    const int tid = threadIdx.x;
    const int g = tid >> 8, t256 = tid & 255;
    const int n = blockIdx.x * 2 + g;
    const int j = t256 >> 1, p = t256 & 1;
    __shared__ float h[2][2][128];   // [buf][group][128]

    #define DECLW(i) float4 w##i;
    REP16(DECLW)
    #undef DECLW
    const float* wsrc = wh + (size_t)(p * 64) * 128 + j;
    #define LDW(i) w##i = make_float4(wsrc[(4*i+0)*128], wsrc[(4*i+1)*128], \
                                      wsrc[(4*i+2)*128], wsrc[(4*i+3)*128]);
    REP16(LDW)
    #undef LDW

    if (t256 < 128) h[0][g][t256] = 0.f;
    __syncthreads();

    float apA = apre[((size_t)1023*NB + n)*128 + j];
    float apB = apre[((size_t)1022*NB + n)*128 + j];
    int cur = 0;

    #define FMAW(i) { float4 hv = *(const float4*)(hb + 4*i); \
        a0 = fmaf(hv.x, w##i.x, a0); a1 = fmaf(hv.y, w##i.y, a1); \
        a2 = fmaf(hv.z, w##i.z, a2); a3 = fmaf(hv.w, w##i.w, a3); }

    for (int t = 1023; t > 0; t -= 2) {
        float apn0 = 0.f;
        if (t - 2 >= 0) apn0 = apre[((size_t)(t-2)*NB + n)*128 + j];
        {
            const float* hb = &h[cur][g][p*64];
            float a0=0.f, a1=0.f, a2=0.f, a3=0.f;
            REP16(FMAW)
            float acc = (a0+a1) + (a2+a3);
            acc += __shfl_xor(acc, 1);
            float hc = fast_tanh(acc + apA);
            if (p == 0) h[cur ^ 1][g][j] = hc;
            else        hcell[((size_t)t*NB + n)*128 + j] = hc;
            bar_sync();
        }
        cur ^= 1;
        float apn1 = 0.f;
        if (t - 3 >= 0) apn1 = apre[((size_t)(t-3)*NB + n)*128 + j];
        {
            const float* hb = &h[cur][g][p*64];
            float a0=0.f, a1=0.f, a2=0.f, a3=0.f;
            REP16(FMAW)
            float acc = (a0+a1) + (a2+a3);
            acc += __shfl_xor(acc, 1);
            float hc = fast_tanh(acc + apB);
            if (p == 0) h[cur ^ 1][g][j] = hc;
            else        hcell[((size_t)(t-1)*NB + n)*128 + j] = hc;
            bar_sync();
        }
        cur ^= 1;
        apA = apn0; apB = apn1;
    }
    #undef FMAW
}

// -------------------------------------------------------------------------
// K3: b = hcell @ wo + bo; alpha = [b[:64], -softplus(b[64:])]
// -------------------------------------------------------------------------
__global__ __launch_bounds__(256) void k_alpha(
    const float* __restrict__ hcell, const float* __restrict__ wo,
    const float* __restrict__ bo, float* __restrict__ alpha)
{
    __shared__ float lhc[8][128];
    const int tid = threadIdx.x;
    const size_t base = (size_t)blockIdx.x * 8 * 128;
    ((float4*)&lhc[0][0])[tid] = ((const float4*)(hcell + base))[tid];
    __syncthreads();

    const int j = tid & 127, rh = tid >> 7;
    float acc[4] = {0,0,0,0};
    for (int i = 0; i < 128; i += 4) {
        float w0 = wo[(i+0)*128 + j];
        float w1v = wo[(i+1)*128 + j];
        float w2v = wo[(i+2)*128 + j];
        float w3 = wo[(i+3)*128 + j];
        #pragma unroll
        for (int q = 0; q < 4; ++q) {
            float4 hv = *(const float4*)&lhc[rh*4+q][i];
            acc[q] += hv.x*w0 + hv.y*w1v + hv.z*w2v + hv.w*w3;
        }
    }
    float bias = bo[j];
    #pragma unroll
    for (int q = 0; q < 4; ++q) {
        float b = acc[q] + bias;
        float val = (j < 64) ? b : -softplus_f(b);
        alpha[base + (size_t)(rh*4+q)*128 + j] = val;
    }
}

// -------------------------------------------------------------------------
// K4: forward posterior scan. 512 threads = 2 batch groups of 256; grid NB/2.
// L1: thread t256 -> hid[t256] (64-dot vs lm broadcast).
// L2: thread (d = t256>>2, p = t256&3) -> quarter-dot, shfl_xor(1)+(2).
// Both weight sets in NAMED float4 registers.
// -------------------------------------------------------------------------
#define LHID_IDX(h) ((h) + 8*((h) >> 6))

__global__ __launch_bounds__(512, 2) void k_fwscan(
    const float* __restrict__ alpha, const float* __restrict__ preU,
    const float* __restrict__ dynw1, const float* __restrict__ dynw2,
    const float* __restrict__ dynb2, const float* __restrict__ qraw,
    const float* __restrict__ m0, const float* __restrict__ v0,
    float* __restrict__ out)
{
    const int tid = threadIdx.x;
    const int g = tid >> 8, t256 = tid & 255;
    const int n = blockIdx.x * 2 + g;
    const int d = t256 >> 2, p = t256 & 3;
    __shared__ float lm[2][2][64];     // [buf][group][64]
    __shared__ float lhid[2][280];     // [group][padded 256]

    #define DECLA(i) float4 A##i;
    REP16(DECLA)
    #undef DECLA
    #define DECLB(i) float4 B##i;
    REP16(DECLB)
    #undef DECLB
    const float* w1src = dynw1 + t256;                     // elem i at [i*256]
    const float* w2src = dynw2 + (size_t)(p * 64) * 64 + d; // elem i at [i*64]
    #define LDA(i) A##i = make_float4(w1src[(4*i+0)*256], w1src[(4*i+1)*256], \
                                      w1src[(4*i+2)*256], w1src[(4*i+3)*256]);
    REP16(LDA)
    #undef LDA
    #define LDB(i) B##i = make_float4(w2src[(4*i+0)*64], w2src[(4*i+1)*64], \
                                      w2src[(4*i+2)*64], w2src[(4*i+3)*64]);
    REP16(LDB)
    #undef LDB

    const float Qv  = softplus_f(qraw[d]);
    const float b2v = dynb2[d];
    float vreg = v0[d];
    if (t256 < 64) lm[0][g][t256] = m0[t256];

    float hpre = preU[(size_t)n * 256 + t256];
    float al1 = alpha[(size_t)n * 128 + d];
    float al2 = alpha[(size_t)n * 128 + 64 + d];
    __syncthreads();

    int cur = 0;
    for (int t = 0; t < T_LEN; ++t) {
        float hpre_n = 0.f, al1_n = 0.f, al2_n = 0.f;
        if (t + 1 < T_LEN) {
            hpre_n = preU[((size_t)(t+1)*NB + n)*256 + t256];
            al1_n  = alpha[((size_t)(t+1)*NB + n)*128 + d];
            al2_n  = alpha[((size_t)(t+1)*NB + n)*128 + 64 + d];
        }

        // L1: hid = tanh(hpre + m @ W1col)
        {
            const float* mb = &lm[cur][g][0];
            float a0=0.f, a1=0.f, a2=0.f, a3=0.f;
            #define FMAA(i) { float4 mv = *(const float4*)(mb + 4*i); \
                a0 = fmaf(mv.x, A##i.x, a0); a1 = fmaf(mv.y, A##i.y, a1); \
                a2 = fmaf(mv.z, A##i.z, a2); a3 = fmaf(mv.w, A##i.w, a3); }
            REP16(FMAA)
            #undef FMAA
            lhid[g][LHID_IDX(t256)] = fast_tanh(hpre + (a0+a1) + (a2+a3));
        }
        bar_sync();

        // L2: quarter-dot + intra-wave reduce + replicated update
        {
            const float* hb2 = &lhid[g][LHID_IDX(p*64)];
            float b0=0.f, b1v=0.f, b2p=0.f, b3=0.f;
            #define FMAB(i) { float4 hv = *(const float4*)(hb2 + 4*i); \
                b0  = fmaf(hv.x, B##i.x, b0);  b1v = fmaf(hv.y, B##i.y, b1v); \
                b2p = fmaf(hv.z, B##i.z, b2p); b3  = fmaf(hv.w, B##i.w, b3); }
            REP16(FMAB)
            #undef FMAB
            float acc = (b0+b1v) + (b2p+b3);
            acc += __shfl_xor(acc, 1);
            acc += __shfl_xor(acc, 2);

            float m_p = acc + b2v;
            float v_p = vreg + Qv;
            float rvp = __builtin_amdgcn_rcpf(v_p);
            float e1 = m_p * rvp + al1;
            float e2 = al2 - 0.5f * rvp;
            float v_s = -0.5f * __builtin_amdgcn_rcpf(e2);
            float m_s = v_s * e1;
            vreg = v_s;
            if (p == 0) lm[cur ^ 1][g][d] = m_s;

            size_t ob = ((size_t)n * T_LEN + t) * 256;
            float val = (p == 0) ? m_s : (p == 1) ? v_s : (p == 2) ? m_p : v_p;
            out[ob + (size_t)p*64 + d] = val;
        }
        bar_sync();
        cur ^= 1;
        hpre = hpre_n; al1 = al1_n; al2 = al2_n;
    }
}

// -------------------------------------------------------------------------
extern "C" void kernel_launch(void* const* d_in, const int* in_sizes, int n_in,
                              void* d_out, int out_size, void* d_ws, size_t ws_size,
                              hipStream_t stream) {
    const float* y      = (const float*)d_in[1];
    const float* u      = (const float*)d_in[2];
    const float* enc_w1 = (const float*)d_in[3];
    const float* enc_b1 = (const float*)d_in[4];
    const float* enc_w2 = (const float*)d_in[5];
    const float* enc_b2 = (const float*)d_in[6];
    const float* bw_wa  = (const float*)d_in[7];
    const float* bw_wh  = (const float*)d_in[8];
    const float* bw_b   = (const float*)d_in[9];
    const float* bw_wo  = (const float*)d_in[10];
    const float* bw_bo  = (const float*)d_in[11];
    const float* dyn_w1 = (const float*)d_in[12];
    const float* dyn_b1 = (const float*)d_in[13];
    const float* dyn_w2 = (const float*)d_in[14];
    const float* dyn_b2 = (const float*)d_in[15];
    const float* q_raw  = (const float*)d_in[16];
    const float* m0     = (const float*)d_in[17];
    const float* v0     = (const float*)d_in[18];
    float* out = (float*)d_out;

    float* ws = (float*)d_ws;
    float* apre  = ws;                  // [T*NB][128]
    float* hcell = ws + 4194304;        // [T*NB][128]
    float* alpha = ws;                  // aliases apre (apre dead after K2)
    float* preU  = ws + 2 * 4194304;    // [T*NB][256]

    k_encoder<<<4096, 256, 0, stream>>>(y, u, enc_w1, enc_b1, enc_w2, enc_b2,
                                        bw_wa, bw_b, dyn_w1, dyn_b1, apre, preU);
    k_bwscan<<<NB/2, 512, 0, stream>>>(apre, bw_wh, hcell);
    k_alpha<<<4096, 256, 0, stream>>>(hcell, bw_wo, bw_bo, alpha);
    k_fwscan<<<NB/2, 512, 0, stream>>>(alpha, preU, dyn_w1, dyn_w2, dyn_b2,
                                       q_raw, m0, v0, out);
}

// Round 4
// 1613.874 us; speedup vs baseline: 1.1330x; 1.1330x over previous
//
#include <hip/hip_runtime.h>
#include <math.h>

// XFADS: N=32, T=1024, D_OBS=128, D_Z=64, D_U=8, H_ENC=256, H_BW=128, H_DYN=256, D_A=128
#define T_LEN 1024
#define NB 32

#define REP16(X) X(0) X(1) X(2) X(3) X(4) X(5) X(6) X(7) X(8) X(9) X(10) X(11) X(12) X(13) X(14) X(15)

// Opaque pin: forces a value to be materialized in VGPRs and makes the
// defining load non-rematerializable (regalloc must keep it live).
#define PIN4(v) asm volatile("" : "+v"(v.x), "+v"(v.y), "+v"(v.z), "+v"(v.w))

__device__ __forceinline__ float softplus_f(float x) {
    return fmaxf(x, 0.f) + log1pf(expf(-fabsf(x)));
}

// fast tanh: 1 - 2/(1+exp2(2*log2e*x)); exp2/rcp are 1-ulp HW ops.
__device__ __forceinline__ float fast_tanh(float x) {
    float e = __builtin_amdgcn_exp2f(x * 2.88539008177792681472f);
    float r = __builtin_amdgcn_rcpf(1.f + e);
    return 1.f - 2.f * r;
}

// raw barrier: drain LDS ops only; global prefetches stay in flight (T4 pattern)
__device__ __forceinline__ void bar_sync() {
    asm volatile("s_waitcnt lgkmcnt(0)" ::: "memory");
    __builtin_amdgcn_s_barrier();
    asm volatile("" ::: "memory");
}

// -------------------------------------------------------------------------
// K1: encoder  h = tanh(y@W1+b1); a = h@W2+b2;
//     apre[t][n][:] = a@bw_wa + bw_b
//     preU[t][n][:] = u@dyn_w1[64:72] + dyn_b1
// -------------------------------------------------------------------------
__global__ __launch_bounds__(256) void k_encoder(
    const float* __restrict__ y, const float* __restrict__ u,
    const float* __restrict__ w1, const float* __restrict__ b1,
    const float* __restrict__ w2, const float* __restrict__ b2,
    const float* __restrict__ wa, const float* __restrict__ bb,
    const float* __restrict__ dynw1, const float* __restrict__ dynb1,
    float* __restrict__ apre, float* __restrict__ preU)
{
    __shared__ float ly[8][128];
    __shared__ float lh[8][256];
    __shared__ float la[8][128];
    __shared__ float lu[8][8];
    const int tid = threadIdx.x;
    const int row0 = blockIdx.x * 8;

    ((float4*)&ly[0][0])[tid] = ((const float4*)(y + (size_t)row0 * 128))[tid];
    if (tid < 16)
        ((float4*)&lu[0][0])[tid] = ((const float4*)(u + (size_t)row0 * 8))[tid];
    __syncthreads();

    {
        float acc[8] = {0,0,0,0,0,0,0,0};
        for (int i = 0; i < 128; i += 4) {
            float w0 = w1[(i+0)*256 + tid];
            float w1v = w1[(i+1)*256 + tid];
            float w2v = w1[(i+2)*256 + tid];
            float w3 = w1[(i+3)*256 + tid];
            #pragma unroll
            for (int r = 0; r < 8; ++r) {
                float4 yv = *(const float4*)&ly[r][i];
                acc[r] += yv.x*w0 + yv.y*w1v + yv.z*w2v + yv.w*w3;
            }
        }
        float bias = b1[tid];
        #pragma unroll
        for (int r = 0; r < 8; ++r) lh[r][tid] = fast_tanh(acc[r] + bias);
    }
    __syncthreads();

    {
        const int d = tid & 127, rh = tid >> 7;
        float acc[4] = {0,0,0,0};
        for (int i = 0; i < 256; i += 4) {
            float w0 = w2[(i+0)*128 + d];
            float w1v = w2[(i+1)*128 + d];
            float w2v = w2[(i+2)*128 + d];
            float w3 = w2[(i+3)*128 + d];
            #pragma unroll
            for (int q = 0; q < 4; ++q) {
                float4 hv = *(const float4*)&lh[rh*4+q][i];
                acc[q] += hv.x*w0 + hv.y*w1v + hv.z*w2v + hv.w*w3;
            }
        }
        float bias = b2[d];
        #pragma unroll
        for (int q = 0; q < 4; ++q) la[rh*4+q][d] = acc[q] + bias;
    }
    __syncthreads();

    {
        const int j = tid & 127, rh = tid >> 7;
        float acc[4] = {0,0,0,0};
        for (int i = 0; i < 128; i += 4) {
            float w0 = wa[(i+0)*128 + j];
            float w1v = wa[(i+1)*128 + j];
            float w2v = wa[(i+2)*128 + j];
            float w3 = wa[(i+3)*128 + j];
            #pragma unroll
            for (int q = 0; q < 4; ++q) {
                float4 av = *(const float4*)&la[rh*4+q][i];
                acc[q] += av.x*w0 + av.y*w1v + av.z*w2v + av.w*w3;
            }
        }
        float bias = bb[j];
        #pragma unroll
        for (int q = 0; q < 4; ++q) {
            int rn = row0 + rh*4 + q;
            int n = rn >> 10, t = rn & 1023;
            apre[((size_t)t*NB + n)*128 + j] = acc[q] + bias;
        }
    }

    {
        float wu[8];
        #pragma unroll
        for (int c = 0; c < 8; ++c) wu[c] = dynw1[(64 + c)*256 + tid];
        float bias = dynb1[tid];
        #pragma unroll
        for (int r = 0; r < 8; ++r) {
            float acc = bias;
            #pragma unroll
            for (int c = 0; c < 8; ++c) acc += lu[r][c] * wu[c];
            int rn = row0 + r;
            int n = rn >> 10, t = rn & 1023;
            preU[((size_t)t*NB + n)*256 + tid] = acc;
        }
    }
}

// -------------------------------------------------------------------------
// K2: backward RNN scan. 256 threads, 1 batch/block, grid NB.
// thread (j = tid>>1, p = tid&1): 64-MAC partial, shfl_xor(1) reduce,
// ONE barrier per step. Weights pinned in VGPRs (non-rematerializable).
// -------------------------------------------------------------------------
__global__ __launch_bounds__(256, 1) void k_bwscan(
    const float* __restrict__ apre, const float* __restrict__ wh,
    float* __restrict__ hcell)
{
    const int n = blockIdx.x;
    const int tid = threadIdx.x;
    const int j = tid >> 1, p = tid & 1;
    __shared__ float h[2][128];

    #define DECLW(i) float4 w##i;
    REP16(DECLW)
    #undef DECLW
    const float* wsrc = wh + (size_t)(p * 64) * 128 + j;
    #define LDW(i) w##i = make_float4(wsrc[(4*i+0)*128], wsrc[(4*i+1)*128], \
                                      wsrc[(4*i+2)*128], wsrc[(4*i+3)*128]); PIN4(w##i);
    REP16(LDW)
    #undef LDW

    if (tid < 128) h[0][tid] = 0.f;
    __syncthreads();

    float apA = apre[((size_t)1023*NB + n)*128 + j];
    float apB = apre[((size_t)1022*NB + n)*128 + j];
    int cur = 0;

    #define FMAW(i) { float4 hv = *(const float4*)(hb + 4*i); \
        a0 = fmaf(hv.x, w##i.x, a0); a1 = fmaf(hv.y, w##i.y, a1); \
        a2 = fmaf(hv.z, w##i.z, a2); a3 = fmaf(hv.w, w##i.w, a3); }

    for (int t = 1023; t > 0; t -= 2) {
        float apn0 = 0.f;
        if (t - 2 >= 0) apn0 = apre[((size_t)(t-2)*NB + n)*128 + j];
        {
            const float* hb = &h[cur][p*64];
            float a0=0.f, a1=0.f, a2=0.f, a3=0.f;
            REP16(FMAW)
            float acc = (a0+a1) + (a2+a3);
            acc += __shfl_xor(acc, 1);
            float hc = fast_tanh(acc + apA);
            if (p == 0) h[cur ^ 1][j] = hc;
            else        hcell[((size_t)t*NB + n)*128 + j] = hc;
            bar_sync();
        }
        cur ^= 1;
        float apn1 = 0.f;
        if (t - 3 >= 0) apn1 = apre[((size_t)(t-3)*NB + n)*128 + j];
        {
            const float* hb = &h[cur][p*64];
            float a0=0.f, a1=0.f, a2=0.f, a3=0.f;
            REP16(FMAW)
            float acc = (a0+a1) + (a2+a3);
            acc += __shfl_xor(acc, 1);
            float hc = fast_tanh(acc + apB);
            if (p == 0) h[cur ^ 1][j] = hc;
            else        hcell[((size_t)(t-1)*NB + n)*128 + j] = hc;
            bar_sync();
        }
        cur ^= 1;
        apA = apn0; apB = apn1;
    }
    #undef FMAW
}

// -------------------------------------------------------------------------
// K3: b = hcell @ wo + bo; alpha = [b[:64], -softplus(b[64:])]
// -------------------------------------------------------------------------
__global__ __launch_bounds__(256) void k_alpha(
    const float* __restrict__ hcell, const float* __restrict__ wo,
    const float* __restrict__ bo, float* __restrict__ alpha)
{
    __shared__ float lhc[8][128];
    const int tid = threadIdx.x;
    const size_t base = (size_t)blockIdx.x * 8 * 128;
    ((float4*)&lhc[0][0])[tid] = ((const float4*)(hcell + base))[tid];
    __syncthreads();

    const int j = tid & 127, rh = tid >> 7;
    float acc[4] = {0,0,0,0};
    for (int i = 0; i < 128; i += 4) {
        float w0 = wo[(i+0)*128 + j];
        float w1v = wo[(i+1)*128 + j];
        float w2v = wo[(i+2)*128 + j];
        float w3 = wo[(i+3)*128 + j];
        #pragma unroll
        for (int q = 0; q < 4; ++q) {
            float4 hv = *(const float4*)&lhc[rh*4+q][i];
            acc[q] += hv.x*w0 + hv.y*w1v + hv.z*w2v + hv.w*w3;
        }
    }
    float bias = bo[j];
    #pragma unroll
    for (int q = 0; q < 4; ++q) {
        float b = acc[q] + bias;
        float val = (j < 64) ? b : -softplus_f(b);
        alpha[base + (size_t)(rh*4+q)*128 + j] = val;
    }
}

// -------------------------------------------------------------------------
// K4: forward posterior scan. 256 threads, 1 batch/block, grid NB.
// L1: thread tid -> hid[tid] (64-dot vs lm broadcast).
// L2: thread (d = tid>>2, p = tid&3) -> quarter-dot, shfl_xor(1)+(2).
// Both weight sets pinned in VGPRs.
// -------------------------------------------------------------------------
#define LHID_IDX(h) ((h) + 8*((h) >> 6))

__global__ __launch_bounds__(256, 1) void k_fwscan(
    const float* __restrict__ alpha, const float* __restrict__ preU,
    const float* __restrict__ dynw1, const float* __restrict__ dynw2,
    const float* __restrict__ dynb2, const float* __restrict__ qraw,
    const float* __restrict__ m0, const float* __restrict__ v0,
    float* __restrict__ out)
{
    const int n = blockIdx.x;
    const int tid = threadIdx.x;
    const int d = tid >> 2, p = tid & 3;
    __shared__ float lm[2][64];
    __shared__ float lhid[280];

    #define DECLA(i) float4 A##i;
    REP16(DECLA)
    #undef DECLA
    #define DECLB(i) float4 B##i;
    REP16(DECLB)
    #undef DECLB
    const float* w1src = dynw1 + tid;                       // elem i at [i*256]
    const float* w2src = dynw2 + (size_t)(p * 64) * 64 + d; // elem i at [i*64]
    #define LDA(i) A##i = make_float4(w1src[(4*i+0)*256], w1src[(4*i+1)*256], \
                                      w1src[(4*i+2)*256], w1src[(4*i+3)*256]); PIN4(A##i);
    REP16(LDA)
    #undef LDA
    #define LDB(i) B##i = make_float4(w2src[(4*i+0)*64], w2src[(4*i+1)*64], \
                                      w2src[(4*i+2)*64], w2src[(4*i+3)*64]); PIN4(B##i);
    REP16(LDB)
    #undef LDB

    const float Qv  = softplus_f(qraw[d]);
    const float b2v = dynb2[d];
    float vreg = v0[d];
    if (tid < 64) lm[0][tid] = m0[tid];

    float hpre = preU[(size_t)n * 256 + tid];
    float al1 = alpha[(size_t)n * 128 + d];
    float al2 = alpha[(size_t)n * 128 + 64 + d];
    __syncthreads();

    int cur = 0;
    for (int t = 0; t < T_LEN; ++t) {
        float hpre_n = 0.f, al1_n = 0.f, al2_n = 0.f;
        if (t + 1 < T_LEN) {
            hpre_n = preU[((size_t)(t+1)*NB + n)*256 + tid];
            al1_n  = alpha[((size_t)(t+1)*NB + n)*128 + d];
            al2_n  = alpha[((size_t)(t+1)*NB + n)*128 + 64 + d];
        }

        // L1: hid = tanh(hpre + m @ W1col)
        {
            const float* mb = &lm[cur][0];
            float a0=0.f, a1=0.f, a2=0.f, a3=0.f;
            #define FMAA(i) { float4 mv = *(const float4*)(mb + 4*i); \
                a0 = fmaf(mv.x, A##i.x, a0); a1 = fmaf(mv.y, A##i.y, a1); \
                a2 = fmaf(mv.z, A##i.z, a2); a3 = fmaf(mv.w, A##i.w, a3); }
            REP16(FMAA)
            #undef FMAA
            lhid[LHID_IDX(tid)] = fast_tanh(hpre + (a0+a1) + (a2+a3));
        }
        bar_sync();

        // L2: quarter-dot + intra-wave reduce + replicated update
        {
            const float* hb2 = &lhid[LHID_IDX(p*64)];
            float b0=0.f, b1v=0.f, b2p=0.f, b3=0.f;
            #define FMAB(i) { float4 hv = *(const float4*)(hb2 + 4*i); \
                b0  = fmaf(hv.x, B##i.x, b0);  b1v = fmaf(hv.y, B##i.y, b1v); \
                b2p = fmaf(hv.z, B##i.z, b2p); b3  = fmaf(hv.w, B##i.w, b3); }
            REP16(FMAB)
            #undef FMAB
            float acc = (b0+b1v) + (b2p+b3);
            acc += __shfl_xor(acc, 1);
            acc += __shfl_xor(acc, 2);

            float m_p = acc + b2v;
            float v_p = vreg + Qv;
            float rvp = __builtin_amdgcn_rcpf(v_p);
            float e1 = m_p * rvp + al1;
            float e2 = al2 - 0.5f * rvp;
            float v_s = -0.5f * __builtin_amdgcn_rcpf(e2);
            float m_s = v_s * e1;
            vreg = v_s;
            if (p == 0) lm[cur ^ 1][d] = m_s;

            size_t ob = ((size_t)n * T_LEN + t) * 256;
            float val = (p == 0) ? m_s : (p == 1) ? v_s : (p == 2) ? m_p : v_p;
            out[ob + (size_t)p*64 + d] = val;
        }
        bar_sync();
        cur ^= 1;
        hpre = hpre_n; al1 = al1_n; al2 = al2_n;
    }
}

// -------------------------------------------------------------------------
extern "C" void kernel_launch(void* const* d_in, const int* in_sizes, int n_in,
                              void* d_out, int out_size, void* d_ws, size_t ws_size,
                              hipStream_t stream) {
    const float* y      = (const float*)d_in[1];
    const float* u      = (const float*)d_in[2];
    const float* enc_w1 = (const float*)d_in[3];
    const float* enc_b1 = (const float*)d_in[4];
    const float* enc_w2 = (const float*)d_in[5];
    const float* enc_b2 = (const float*)d_in[6];
    const float* bw_wa  = (const float*)d_in[7];
    const float* bw_wh  = (const float*)d_in[8];
    const float* bw_b   = (const float*)d_in[9];
    const float* bw_wo  = (const float*)d_in[10];
    const float* bw_bo  = (const float*)d_in[11];
    const float* dyn_w1 = (const float*)d_in[12];
    const float* dyn_b1 = (const float*)d_in[13];
    const float* dyn_w2 = (const float*)d_in[14];
    const float* dyn_b2 = (const float*)d_in[15];
    const float* q_raw  = (const float*)d_in[16];
    const float* m0     = (const float*)d_in[17];
    const float* v0     = (const float*)d_in[18];
    float* out = (float*)d_out;

    float* ws = (float*)d_ws;
    float* apre  = ws;                  // [T*NB][128]
    float* hcell = ws + 4194304;        // [T*NB][128]
    float* alpha = ws;                  // aliases apre (apre dead after K2)
    float* preU  = ws + 2 * 4194304;    // [T*NB][256]

    k_encoder<<<4096, 256, 0, stream>>>(y, u, enc_w1, enc_b1, enc_w2, enc_b2,
                                        bw_wa, bw_b, dyn_w1, dyn_b1, apre, preU);
    k_bwscan<<<NB, 256, 0, stream>>>(apre, bw_wh, hcell);
    k_alpha<<<4096, 256, 0, stream>>>(hcell, bw_wo, bw_bo, alpha);
    k_fwscan<<<NB, 256, 0, stream>>>(alpha, preU, dyn_w1, dyn_w2, dyn_b2,
                                     q_raw, m0, v0, out);
}

// Round 5
// 1569.847 us; speedup vs baseline: 1.1648x; 1.0280x over previous
//
#include <hip/hip_runtime.h>
#include <math.h>

// XFADS: N=32, T=1024, D_OBS=128, D_Z=64, D_U=8, H_ENC=256, H_BW=128, H_DYN=256, D_A=128
#define T_LEN 1024
#define NB 32

__device__ __forceinline__ float softplus_f(float x) {
    return fmaxf(x, 0.f) + log1pf(expf(-fabsf(x)));
}

// fast tanh: 1 - 2/(1+exp2(2*log2e*x)); exp2/rcp are 1-ulp HW ops.
__device__ __forceinline__ float fast_tanh(float x) {
    float e = __builtin_amdgcn_exp2f(x * 2.88539008177792681472f);
    float r = __builtin_amdgcn_rcpf(1.f + e);
    return 1.f - 2.f * r;
}

// raw barrier: drain LDS ops only; global prefetches stay in flight (T4 pattern)
__device__ __forceinline__ void bar_sync() {
    asm volatile("s_waitcnt lgkmcnt(0)" ::: "memory");
    __builtin_amdgcn_s_barrier();
    asm volatile("" ::: "memory");
}

// -------------------------------------------------------------------------
// K1: encoder  h = tanh(y@W1+b1); a = h@W2+b2;
//     apre[t][n][:] = a@bw_wa + bw_b
//     preU[t][n][:] = u@dyn_w1[64:72] + dyn_b1
// -------------------------------------------------------------------------
__global__ __launch_bounds__(256) void k_encoder(
    const float* __restrict__ y, const float* __restrict__ u,
    const float* __restrict__ w1, const float* __restrict__ b1,
    const float* __restrict__ w2, const float* __restrict__ b2,
    const float* __restrict__ wa, const float* __restrict__ bb,
    const float* __restrict__ dynw1, const float* __restrict__ dynb1,
    float* __restrict__ apre, float* __restrict__ preU)
{
    __shared__ float ly[8][128];
    __shared__ float lh[8][256];
    __shared__ float la[8][128];
    __shared__ float lu[8][8];
    const int tid = threadIdx.x;
    const int row0 = blockIdx.x * 8;

    ((float4*)&ly[0][0])[tid] = ((const float4*)(y + (size_t)row0 * 128))[tid];
    if (tid < 16)
        ((float4*)&lu[0][0])[tid] = ((const float4*)(u + (size_t)row0 * 8))[tid];
    __syncthreads();

    {
        float acc[8] = {0,0,0,0,0,0,0,0};
        for (int i = 0; i < 128; i += 4) {
            float w0 = w1[(i+0)*256 + tid];
            float w1v = w1[(i+1)*256 + tid];
            float w2v = w1[(i+2)*256 + tid];
            float w3 = w1[(i+3)*256 + tid];
            #pragma unroll
            for (int r = 0; r < 8; ++r) {
                float4 yv = *(const float4*)&ly[r][i];
                acc[r] += yv.x*w0 + yv.y*w1v + yv.z*w2v + yv.w*w3;
            }
        }
        float bias = b1[tid];
        #pragma unroll
        for (int r = 0; r < 8; ++r) lh[r][tid] = fast_tanh(acc[r] + bias);
    }
    __syncthreads();

    {
        const int d = tid & 127, rh = tid >> 7;
        float acc[4] = {0,0,0,0};
        for (int i = 0; i < 256; i += 4) {
            float w0 = w2[(i+0)*128 + d];
            float w1v = w2[(i+1)*128 + d];
            float w2v = w2[(i+2)*128 + d];
            float w3 = w2[(i+3)*128 + d];
            #pragma unroll
            for (int q = 0; q < 4; ++q) {
                float4 hv = *(const float4*)&lh[rh*4+q][i];
                acc[q] += hv.x*w0 + hv.y*w1v + hv.z*w2v + hv.w*w3;
            }
        }
        float bias = b2[d];
        #pragma unroll
        for (int q = 0; q < 4; ++q) la[rh*4+q][d] = acc[q] + bias;
    }
    __syncthreads();

    {
        const int j = tid & 127, rh = tid >> 7;
        float acc[4] = {0,0,0,0};
        for (int i = 0; i < 128; i += 4) {
            float w0 = wa[(i+0)*128 + j];
            float w1v = wa[(i+1)*128 + j];
            float w2v = wa[(i+2)*128 + j];
            float w3 = wa[(i+3)*128 + j];
            #pragma unroll
            for (int q = 0; q < 4; ++q) {
                float4 av = *(const float4*)&la[rh*4+q][i];
                acc[q] += av.x*w0 + av.y*w1v + av.z*w2v + av.w*w3;
            }
        }
        float bias = bb[j];
        #pragma unroll
        for (int q = 0; q < 4; ++q) {
            int rn = row0 + rh*4 + q;
            int n = rn >> 10, t = rn & 1023;
            apre[((size_t)t*NB + n)*128 + j] = acc[q] + bias;
        }
    }

    {
        float wu[8];
        #pragma unroll
        for (int c = 0; c < 8; ++c) wu[c] = dynw1[(64 + c)*256 + tid];
        float bias = dynb1[tid];
        #pragma unroll
        for (int r = 0; r < 8; ++r) {
            float acc = bias;
            #pragma unroll
            for (int c = 0; c < 8; ++c) acc += lu[r][c] * wu[c];
            int rn = row0 + r;
            int n = rn >> 10, t = rn & 1023;
            preU[((size_t)t*NB + n)*256 + tid] = acc;
        }
    }
}

// -------------------------------------------------------------------------
// K2: backward RNN scan. 1024 threads, 1 batch/block, grid NB.
// thread (j = tid>>3, p = tid&7): 16-MAC partial of column j over
// h[p*16..p*16+15]; shfl_xor(1,2,4) butterfly -> all 8 lanes hold sum.
// Per-thread weights: 16 floats (4 float4) -> comfortably VGPR-resident.
// ONE barrier per step; apre prefetch ring distance 2.
// -------------------------------------------------------------------------
__global__ __launch_bounds__(1024, 1) void k_bwscan(
    const float* __restrict__ apre, const float* __restrict__ wh,
    float* __restrict__ hcell)
{
    const int n = blockIdx.x;
    const int tid = threadIdx.x;
    const int j = tid >> 3, p = tid & 7;
    __shared__ float h[2][128];

    float4 wA, wB, wC, wD;
    {
        const float* wsrc = wh + (size_t)(p * 16) * 128 + j;
        wA = make_float4(wsrc[0*128], wsrc[1*128], wsrc[2*128], wsrc[3*128]);
        wB = make_float4(wsrc[4*128], wsrc[5*128], wsrc[6*128], wsrc[7*128]);
        wC = make_float4(wsrc[8*128], wsrc[9*128], wsrc[10*128], wsrc[11*128]);
        wD = make_float4(wsrc[12*128], wsrc[13*128], wsrc[14*128], wsrc[15*128]);
    }

    if (tid < 128) h[0][tid] = 0.f;
    __syncthreads();

    float apA = apre[((size_t)1023*NB + n)*128 + j];
    float apB = apre[((size_t)1022*NB + n)*128 + j];
    int cur = 0;

    for (int t = 1023; t >= 0; --t) {
        float apN = 0.f;
        if (t >= 2) apN = apre[((size_t)(t-2)*NB + n)*128 + j];

        const float* hb = &h[cur][p*16];
        float4 h0 = *(const float4*)(hb + 0);
        float4 h1 = *(const float4*)(hb + 4);
        float4 h2 = *(const float4*)(hb + 8);
        float4 h3 = *(const float4*)(hb + 12);
        float a0 = h0.x*wA.x, a1 = h0.y*wA.y, a2 = h0.z*wA.z, a3 = h0.w*wA.w;
        a0 = fmaf(h1.x, wB.x, a0); a1 = fmaf(h1.y, wB.y, a1);
        a2 = fmaf(h1.z, wB.z, a2); a3 = fmaf(h1.w, wB.w, a3);
        a0 = fmaf(h2.x, wC.x, a0); a1 = fmaf(h2.y, wC.y, a1);
        a2 = fmaf(h2.z, wC.z, a2); a3 = fmaf(h2.w, wC.w, a3);
        a0 = fmaf(h3.x, wD.x, a0); a1 = fmaf(h3.y, wD.y, a1);
        a2 = fmaf(h3.z, wD.z, a2); a3 = fmaf(h3.w, wD.w, a3);
        float acc = (a0+a1) + (a2+a3);
        acc += __shfl_xor(acc, 1);
        acc += __shfl_xor(acc, 2);
        acc += __shfl_xor(acc, 4);
        float hc = fast_tanh(acc + apA);
        if (p == 0) h[cur ^ 1][j] = hc;
        else if (p == 1) hcell[((size_t)t*NB + n)*128 + j] = hc;
        bar_sync();
        cur ^= 1;
        apA = apB; apB = apN;
    }
}

// -------------------------------------------------------------------------
// K3: b = hcell @ wo + bo; alpha = [b[:64], -softplus(b[64:])]
// -------------------------------------------------------------------------
__global__ __launch_bounds__(256) void k_alpha(
    const float* __restrict__ hcell, const float* __restrict__ wo,
    const float* __restrict__ bo, float* __restrict__ alpha)
{
    __shared__ float lhc[8][128];
    const int tid = threadIdx.x;
    const size_t base = (size_t)blockIdx.x * 8 * 128;
    ((float4*)&lhc[0][0])[tid] = ((const float4*)(hcell + base))[tid];
    __syncthreads();

    const int j = tid & 127, rh = tid >> 7;
    float acc[4] = {0,0,0,0};
    for (int i = 0; i < 128; i += 4) {
        float w0 = wo[(i+0)*128 + j];
        float w1v = wo[(i+1)*128 + j];
        float w2v = wo[(i+2)*128 + j];
        float w3 = wo[(i+3)*128 + j];
        #pragma unroll
        for (int q = 0; q < 4; ++q) {
            float4 hv = *(const float4*)&lhc[rh*4+q][i];
            acc[q] += hv.x*w0 + hv.y*w1v + hv.z*w2v + hv.w*w3;
        }
    }
    float bias = bo[j];
    #pragma unroll
    for (int q = 0; q < 4; ++q) {
        float b = acc[q] + bias;
        float val = (j < 64) ? b : -softplus_f(b);
        alpha[base + (size_t)(rh*4+q)*128 + j] = val;
    }
}

// -------------------------------------------------------------------------
// K4: forward posterior scan. 1024 threads, 1 batch/block, grid NB.
// L1: thread (hh = tid>>2, pp = tid&3): 16-MAC partial of hidden hh over
//     m[pp*16..+15]; shfl_xor(1,2) -> pp==0 writes lhid[hh].
// L2: thread (d2 = tid>>4, qq = tid&15): 16-MAC partial of output d2 over
//     hid[qq*16..+15]; shfl_xor(1,2,4,8) butterfly -> all lanes hold sum;
//     replicated update; qq<4 store the 4 outputs; qq==0 writes lm.
// Per-thread weights: 32 floats -> VGPR-resident under allocator's budget.
// -------------------------------------------------------------------------
#define LH(x) ((x) + (((x) >> 4) << 2))   // pad 4 words per 16 -> spread banks

__global__ __launch_bounds__(1024, 1) void k_fwscan(
    const float* __restrict__ alpha, const float* __restrict__ preU,
    const float* __restrict__ dynw1, const float* __restrict__ dynw2,
    const float* __restrict__ dynb2, const float* __restrict__ qraw,
    const float* __restrict__ m0, const float* __restrict__ v0,
    float* __restrict__ out)
{
    const int n = blockIdx.x;
    const int tid = threadIdx.x;
    const int hh = tid >> 2, pp = tid & 3;
    const int d2 = tid >> 4, qq = tid & 15;
    __shared__ float lm[2][64];
    __shared__ float lhid[320];

    float4 u0, u1, u2, u3;   // W1[pp*16+i][hh], i<16
    {
        const float* s = dynw1 + (size_t)(pp * 16) * 256 + hh;
        u0 = make_float4(s[0*256], s[1*256], s[2*256], s[3*256]);
        u1 = make_float4(s[4*256], s[5*256], s[6*256], s[7*256]);
        u2 = make_float4(s[8*256], s[9*256], s[10*256], s[11*256]);
        u3 = make_float4(s[12*256], s[13*256], s[14*256], s[15*256]);
    }
    float4 v0r, v1r, v2r, v3r;  // W2[qq*16+i][d2], i<16
    {
        const float* s = dynw2 + (size_t)(qq * 16) * 64 + d2;
        v0r = make_float4(s[0*64], s[1*64], s[2*64], s[3*64]);
        v1r = make_float4(s[4*64], s[5*64], s[6*64], s[7*64]);
        v2r = make_float4(s[8*64], s[9*64], s[10*64], s[11*64]);
        v3r = make_float4(s[12*64], s[13*64], s[14*64], s[15*64]);
    }

    const float Qv  = softplus_f(qraw[d2]);
    const float b2v = dynb2[d2];
    float vreg = v0[d2];
    if (tid < 64) lm[0][tid] = m0[tid];

    // prefetch ring, distance 2: (hpre, al1, al2) for t and t+1
    float hp0 = preU[((size_t)0*NB + n)*256 + hh];
    float a10 = alpha[((size_t)0*NB + n)*128 + d2];
    float a20 = alpha[((size_t)0*NB + n)*128 + 64 + d2];
    float hp1 = preU[((size_t)1*NB + n)*256 + hh];
    float a11 = alpha[((size_t)1*NB + n)*128 + d2];
    float a21 = alpha[((size_t)1*NB + n)*128 + 64 + d2];
    __syncthreads();

    int cur = 0;
    for (int t = 0; t < T_LEN; ++t) {
        float hpN = 0.f, a1N = 0.f, a2N = 0.f;
        if (t + 2 < T_LEN) {
            hpN = preU[((size_t)(t+2)*NB + n)*256 + hh];
            a1N = alpha[((size_t)(t+2)*NB + n)*128 + d2];
            a2N = alpha[((size_t)(t+2)*NB + n)*128 + 64 + d2];
        }

        // L1: partial dot over m slice, pair+quad reduce
        {
            const float* mb = &lm[cur][pp*16];
            float4 m0v = *(const float4*)(mb + 0);
            float4 m1v = *(const float4*)(mb + 4);
            float4 m2v = *(const float4*)(mb + 8);
            float4 m3v = *(const float4*)(mb + 12);
            float a0 = m0v.x*u0.x, a1 = m0v.y*u0.y, a2 = m0v.z*u0.z, a3 = m0v.w*u0.w;
            a0 = fmaf(m1v.x, u1.x, a0); a1 = fmaf(m1v.y, u1.y, a1);
            a2 = fmaf(m1v.z, u1.z, a2); a3 = fmaf(m1v.w, u1.w, a3);
            a0 = fmaf(m2v.x, u2.x, a0); a1 = fmaf(m2v.y, u2.y, a1);
            a2 = fmaf(m2v.z, u2.z, a2); a3 = fmaf(m2v.w, u2.w, a3);
            a0 = fmaf(m3v.x, u3.x, a0); a1 = fmaf(m3v.y, u3.y, a1);
            a2 = fmaf(m3v.z, u3.z, a2); a3 = fmaf(m3v.w, u3.w, a3);
            float acc = (a0+a1) + (a2+a3);
            acc += __shfl_xor(acc, 1);
            acc += __shfl_xor(acc, 2);
            if (pp == 0) lhid[LH(hh)] = fast_tanh(hp0 + acc);
        }
        bar_sync();

        // L2: partial dot over hid slice, 4-level butterfly -> full sum
        {
            const float* hb = &lhid[LH(qq*16)];
            float4 h0 = *(const float4*)(hb + 0);
            float4 h1 = *(const float4*)(hb + 4);
            float4 h2 = *(const float4*)(hb + 8);
            float4 h3 = *(const float4*)(hb + 12);
            float b0 = h0.x*v0r.x, b1 = h0.y*v0r.y, b2 = h0.z*v0r.z, b3 = h0.w*v0r.w;
            b0 = fmaf(h1.x, v1r.x, b0); b1 = fmaf(h1.y, v1r.y, b1);
            b2 = fmaf(h1.z, v1r.z, b2); b3 = fmaf(h1.w, v1r.w, b3);
            b0 = fmaf(h2.x, v2r.x, b0); b1 = fmaf(h2.y, v2r.y, b1);
            b2 = fmaf(h2.z, v2r.z, b2); b3 = fmaf(h2.w, v2r.w, b3);
            b0 = fmaf(h3.x, v3r.x, b0); b1 = fmaf(h3.y, v3r.y, b1);
            b2 = fmaf(h3.z, v3r.z, b2); b3 = fmaf(h3.w, v3r.w, b3);
            float acc = (b0+b1) + (b2+b3);
            acc += __shfl_xor(acc, 1);
            acc += __shfl_xor(acc, 2);
            acc += __shfl_xor(acc, 4);
            acc += __shfl_xor(acc, 8);

            float m_p = acc + b2v;
            float v_p = vreg + Qv;
            float rvp = __builtin_amdgcn_rcpf(v_p);
            float e1 = m_p * rvp + a10;
            float e2 = a20 - 0.5f * rvp;
            float v_s = -0.5f * __builtin_amdgcn_rcpf(e2);
            float m_s = v_s * e1;
            vreg = v_s;
            if (qq == 0) lm[cur ^ 1][d2] = m_s;

            if (qq < 4) {
                size_t ob = ((size_t)n * T_LEN + t) * 256;
                float val = (qq == 0) ? m_s : (qq == 1) ? v_s : (qq == 2) ? m_p : v_p;
                out[ob + (size_t)qq*64 + d2] = val;
            }
        }
        bar_sync();
        cur ^= 1;
        hp0 = hp1; a10 = a11; a20 = a21;
        hp1 = hpN; a11 = a1N; a21 = a2N;
    }
}

// -------------------------------------------------------------------------
extern "C" void kernel_launch(void* const* d_in, const int* in_sizes, int n_in,
                              void* d_out, int out_size, void* d_ws, size_t ws_size,
                              hipStream_t stream) {
    const float* y      = (const float*)d_in[1];
    const float* u      = (const float*)d_in[2];
    const float* enc_w1 = (const float*)d_in[3];
    const float* enc_b1 = (const float*)d_in[4];
    const float* enc_w2 = (const float*)d_in[5];
    const float* enc_b2 = (const float*)d_in[6];
    const float* bw_wa  = (const float*)d_in[7];
    const float* bw_wh  = (const float*)d_in[8];
    const float* bw_b   = (const float*)d_in[9];
    const float* bw_wo  = (const float*)d_in[10];
    const float* bw_bo  = (const float*)d_in[11];
    const float* dyn_w1 = (const float*)d_in[12];
    const float* dyn_b1 = (const float*)d_in[13];
    const float* dyn_w2 = (const float*)d_in[14];
    const float* dyn_b2 = (const float*)d_in[15];
    const float* q_raw  = (const float*)d_in[16];
    const float* m0     = (const float*)d_in[17];
    const float* v0     = (const float*)d_in[18];
    float* out = (float*)d_out;

    float* ws = (float*)d_ws;
    float* apre  = ws;                  // [T*NB][128]
    float* hcell = ws + 4194304;        // [T*NB][128]
    float* alpha = ws;                  // aliases apre (apre dead after K2)
    float* preU  = ws + 2 * 4194304;    // [T*NB][256]

    k_encoder<<<4096, 256, 0, stream>>>(y, u, enc_w1, enc_b1, enc_w2, enc_b2,
                                        bw_wa, bw_b, dyn_w1, dyn_b1, apre, preU);
    k_bwscan<<<NB, 1024, 0, stream>>>(apre, bw_wh, hcell);
    k_alpha<<<4096, 256, 0, stream>>>(hcell, bw_wo, bw_bo, alpha);
    k_fwscan<<<NB, 1024, 0, stream>>>(alpha, preU, dyn_w1, dyn_w2, dyn_b2,
                                      q_raw, m0, v0, out);
}

// Round 6
// 1418.278 us; speedup vs baseline: 1.2893x; 1.1069x over previous
//
#include <hip/hip_runtime.h>
#include <math.h>

// XFADS: N=32, T=1024, D_OBS=128, D_Z=64, D_U=8, H_ENC=256, H_BW=128, H_DYN=256, D_A=128
#define T_LEN 1024
#define NB 32

typedef _Float16 h2 __attribute__((ext_vector_type(2)));

__device__ __forceinline__ h2 f2h2(float f) { return __builtin_bit_cast(h2, f); }

__device__ __forceinline__ float dot2(h2 a, h2 b, float c) {
#if __has_builtin(__builtin_amdgcn_fdot2)
    return __builtin_amdgcn_fdot2(a, b, c, false);
#else
    return fmaf((float)a[0], (float)b[0], fmaf((float)a[1], (float)b[1], c));
#endif
}

__device__ __forceinline__ float softplus_f(float x) {
    return fmaxf(x, 0.f) + log1pf(expf(-fabsf(x)));
}

// fast tanh: 1 - 2/(1+exp2(2*log2e*x)); exp2/rcp are 1-ulp HW ops.
__device__ __forceinline__ float fast_tanh(float x) {
    float e = __builtin_amdgcn_exp2f(x * 2.88539008177792681472f);
    float r = __builtin_amdgcn_rcpf(1.f + e);
    return 1.f - 2.f * r;
}

// raw barrier: drain LDS ops only; global prefetches stay in flight (T4 pattern)
__device__ __forceinline__ void bar_sync() {
    asm volatile("s_waitcnt lgkmcnt(0)" ::: "memory");
    __builtin_amdgcn_s_barrier();
    asm volatile("" ::: "memory");
}

// -------------------------------------------------------------------------
// K1: encoder  h = tanh(y@W1+b1); a = h@W2+b2;
//     apre[t][n][:] = a@bw_wa + bw_b
//     preU[t][n][:] = u@dyn_w1[64:72] + dyn_b1
// -------------------------------------------------------------------------
__global__ __launch_bounds__(256) void k_encoder(
    const float* __restrict__ y, const float* __restrict__ u,
    const float* __restrict__ w1, const float* __restrict__ b1,
    const float* __restrict__ w2, const float* __restrict__ b2,
    const float* __restrict__ wa, const float* __restrict__ bb,
    const float* __restrict__ dynw1, const float* __restrict__ dynb1,
    float* __restrict__ apre, float* __restrict__ preU)
{
    __shared__ float ly[8][128];
    __shared__ float lh[8][256];
    __shared__ float la[8][128];
    __shared__ float lu[8][8];
    const int tid = threadIdx.x;
    const int row0 = blockIdx.x * 8;

    ((float4*)&ly[0][0])[tid] = ((const float4*)(y + (size_t)row0 * 128))[tid];
    if (tid < 16)
        ((float4*)&lu[0][0])[tid] = ((const float4*)(u + (size_t)row0 * 8))[tid];
    __syncthreads();

    {
        float acc[8] = {0,0,0,0,0,0,0,0};
        for (int i = 0; i < 128; i += 4) {
            float w0 = w1[(i+0)*256 + tid];
            float w1v = w1[(i+1)*256 + tid];
            float w2v = w1[(i+2)*256 + tid];
            float w3 = w1[(i+3)*256 + tid];
            #pragma unroll
            for (int r = 0; r < 8; ++r) {
                float4 yv = *(const float4*)&ly[r][i];
                acc[r] += yv.x*w0 + yv.y*w1v + yv.z*w2v + yv.w*w3;
            }
        }
        float bias = b1[tid];
        #pragma unroll
        for (int r = 0; r < 8; ++r) lh[r][tid] = fast_tanh(acc[r] + bias);
    }
    __syncthreads();

    {
        const int d = tid & 127, rh = tid >> 7;
        float acc[4] = {0,0,0,0};
        for (int i = 0; i < 256; i += 4) {
            float w0 = w2[(i+0)*128 + d];
            float w1v = w2[(i+1)*128 + d];
            float w2v = w2[(i+2)*128 + d];
            float w3 = w2[(i+3)*128 + d];
            #pragma unroll
            for (int q = 0; q < 4; ++q) {
                float4 hv = *(const float4*)&lh[rh*4+q][i];
                acc[q] += hv.x*w0 + hv.y*w1v + hv.z*w2v + hv.w*w3;
            }
        }
        float bias = b2[d];
        #pragma unroll
        for (int q = 0; q < 4; ++q) la[rh*4+q][d] = acc[q] + bias;
    }
    __syncthreads();

    {
        const int j = tid & 127, rh = tid >> 7;
        float acc[4] = {0,0,0,0};
        for (int i = 0; i < 128; i += 4) {
            float w0 = wa[(i+0)*128 + j];
            float w1v = wa[(i+1)*128 + j];
            float w2v = wa[(i+2)*128 + j];
            float w3 = wa[(i+3)*128 + j];
            #pragma unroll
            for (int q = 0; q < 4; ++q) {
                float4 av = *(const float4*)&la[rh*4+q][i];
                acc[q] += av.x*w0 + av.y*w1v + av.z*w2v + av.w*w3;
            }
        }
        float bias = bb[j];
        #pragma unroll
        for (int q = 0; q < 4; ++q) {
            int rn = row0 + rh*4 + q;
            int n = rn >> 10, t = rn & 1023;
            apre[((size_t)t*NB + n)*128 + j] = acc[q] + bias;
        }
    }

    {
        float wu[8];
        #pragma unroll
        for (int c = 0; c < 8; ++c) wu[c] = dynw1[(64 + c)*256 + tid];
        float bias = dynb1[tid];
        #pragma unroll
        for (int r = 0; r < 8; ++r) {
            float acc = bias;
            #pragma unroll
            for (int c = 0; c < 8; ++c) acc += lu[r][c] * wu[c];
            int rn = row0 + r;
            int n = rn >> 10, t = rn & 1023;
            preU[((size_t)t*NB + n)*256 + tid] = acc;
        }
    }
}

// -------------------------------------------------------------------------
// K2: backward RNN scan. 1024 threads, 1 batch/block, grid NB.
// thread (j = tid>>3, p = tid&7): 16-MAC partial (8 x v_dot2) of column j
// over h_f16[p*16..+15]; shfl_xor(1,2,4) -> all 8 lanes hold sum.
// State in LDS as f16 (2 x ds_read_b128 per thread), weights as 8 packed
// f16x2 VGPRs. ONE barrier per step; apre prefetch ring distance 2.
// -------------------------------------------------------------------------
__global__ __launch_bounds__(1024, 1) void k_bwscan(
    const float* __restrict__ apre, const float* __restrict__ wh,
    float* __restrict__ hcell)
{
    const int n = blockIdx.x;
    const int tid = threadIdx.x;
    const int j = tid >> 3, p = tid & 7;
    __shared__ _Float16 h[2][128];

    h2 w0, w1, w2, w3, w4, w5, w6, w7;   // Wh[p*16+2k..+1][j] packed
    {
        const float* s = wh + (size_t)(p * 16) * 128 + j;
        w0 = h2{(_Float16)s[0*128], (_Float16)s[1*128]};
        w1 = h2{(_Float16)s[2*128], (_Float16)s[3*128]};
        w2 = h2{(_Float16)s[4*128], (_Float16)s[5*128]};
        w3 = h2{(_Float16)s[6*128], (_Float16)s[7*128]};
        w4 = h2{(_Float16)s[8*128], (_Float16)s[9*128]};
        w5 = h2{(_Float16)s[10*128], (_Float16)s[11*128]};
        w6 = h2{(_Float16)s[12*128], (_Float16)s[13*128]};
        w7 = h2{(_Float16)s[14*128], (_Float16)s[15*128]};
    }

    if (tid < 128) h[0][tid] = (_Float16)0.f;
    __syncthreads();

    float apA = apre[((size_t)1023*NB + n)*128 + j];
    float apB = apre[((size_t)1022*NB + n)*128 + j];
    int cur = 0;

    for (int t = 1023; t >= 0; --t) {
        float apN = 0.f;
        if (t >= 2) apN = apre[((size_t)(t-2)*NB + n)*128 + j];

        const _Float16* hb = &h[cur][p*16];
        float4 r0 = *(const float4*)hb;          // 8 f16
        float4 r1 = *(const float4*)(hb + 8);    // 8 f16
        float c0 = dot2(f2h2(r0.x), w0, 0.f);
        float c1 = dot2(f2h2(r0.y), w1, 0.f);
        float c2 = dot2(f2h2(r0.z), w2, 0.f);
        float c3 = dot2(f2h2(r0.w), w3, 0.f);
        c0 = dot2(f2h2(r1.x), w4, c0);
        c1 = dot2(f2h2(r1.y), w5, c1);
        c2 = dot2(f2h2(r1.z), w6, c2);
        c3 = dot2(f2h2(r1.w), w7, c3);
        float acc = (c0+c1) + (c2+c3);
        acc += __shfl_xor(acc, 1);
        acc += __shfl_xor(acc, 2);
        acc += __shfl_xor(acc, 4);
        float hc = fast_tanh(acc + apA);
        if (p == 0) h[cur ^ 1][j] = (_Float16)hc;
        else if (p == 1) hcell[((size_t)t*NB + n)*128 + j] = hc;
        bar_sync();
        cur ^= 1;
        apA = apB; apB = apN;
    }
}

// -------------------------------------------------------------------------
// K3: b = hcell @ wo + bo; alpha = [b[:64], -softplus(b[64:])]
// -------------------------------------------------------------------------
__global__ __launch_bounds__(256) void k_alpha(
    const float* __restrict__ hcell, const float* __restrict__ wo,
    const float* __restrict__ bo, float* __restrict__ alpha)
{
    __shared__ float lhc[8][128];
    const int tid = threadIdx.x;
    const size_t base = (size_t)blockIdx.x * 8 * 128;
    ((float4*)&lhc[0][0])[tid] = ((const float4*)(hcell + base))[tid];
    __syncthreads();

    const int j = tid & 127, rh = tid >> 7;
    float acc[4] = {0,0,0,0};
    for (int i = 0; i < 128; i += 4) {
        float w0 = wo[(i+0)*128 + j];
        float w1v = wo[(i+1)*128 + j];
        float w2v = wo[(i+2)*128 + j];
        float w3 = wo[(i+3)*128 + j];
        #pragma unroll
        for (int q = 0; q < 4; ++q) {
            float4 hv = *(const float4*)&lhc[rh*4+q][i];
            acc[q] += hv.x*w0 + hv.y*w1v + hv.z*w2v + hv.w*w3;
        }
    }
    float bias = bo[j];
    #pragma unroll
    for (int q = 0; q < 4; ++q) {
        float b = acc[q] + bias;
        float val = (j < 64) ? b : -softplus_f(b);
        alpha[base + (size_t)(rh*4+q)*128 + j] = val;
    }
}

// -------------------------------------------------------------------------
// K4: forward posterior scan. 1024 threads, 1 batch/block, grid NB.
// L1: (hh = tid>>2, pp = tid&3): 16-MAC (8 dot2) partial of hidden hh over
//     m_f16[pp*16..+15]; shfl_xor(1,2) -> pp==0 writes lhid[hh] (f16).
// L2: (d2 = tid>>4, qq = tid&15): 16-MAC (8 dot2) partial of output d2 over
//     hid_f16[qq*16..+15]; shfl_xor(1,2,4,8) -> all lanes; replicated
//     update; qq<4 store the 4 outputs; qq==0 writes lm (f16).
// -------------------------------------------------------------------------
#define LHF(x) ((x) + (((x) >> 4) << 3))   // pad 8 f16 (16B) per 16-elem chunk

__global__ __launch_bounds__(1024, 1) void k_fwscan(
    const float* __restrict__ alpha, const float* __restrict__ preU,
    const float* __restrict__ dynw1, const float* __restrict__ dynw2,
    const float* __restrict__ dynb2, const float* __restrict__ qraw,
    const float* __restrict__ m0, const float* __restrict__ v0,
    float* __restrict__ out)
{
    const int n = blockIdx.x;
    const int tid = threadIdx.x;
    const int hh = tid >> 2, pp = tid & 3;
    const int d2 = tid >> 4, qq = tid & 15;
    __shared__ _Float16 lm[2][64];
    __shared__ _Float16 lhid[384];

    h2 u0, u1, u2, u3, u4, u5, u6, u7;   // W1[pp*16+2k..+1][hh]
    {
        const float* s = dynw1 + (size_t)(pp * 16) * 256 + hh;
        u0 = h2{(_Float16)s[0*256], (_Float16)s[1*256]};
        u1 = h2{(_Float16)s[2*256], (_Float16)s[3*256]};
        u2 = h2{(_Float16)s[4*256], (_Float16)s[5*256]};
        u3 = h2{(_Float16)s[6*256], (_Float16)s[7*256]};
        u4 = h2{(_Float16)s[8*256], (_Float16)s[9*256]};
        u5 = h2{(_Float16)s[10*256], (_Float16)s[11*256]};
        u6 = h2{(_Float16)s[12*256], (_Float16)s[13*256]};
        u7 = h2{(_Float16)s[14*256], (_Float16)s[15*256]};
    }
    h2 v0p, v1p, v2p, v3p, v4p, v5p, v6p, v7p;  // W2[qq*16+2k..+1][d2]
    {
        const float* s = dynw2 + (size_t)(qq * 16) * 64 + d2;
        v0p = h2{(_Float16)s[0*64], (_Float16)s[1*64]};
        v1p = h2{(_Float16)s[2*64], (_Float16)s[3*64]};
        v2p = h2{(_Float16)s[4*64], (_Float16)s[5*64]};
        v3p = h2{(_Float16)s[6*64], (_Float16)s[7*64]};
        v4p = h2{(_Float16)s[8*64], (_Float16)s[9*64]};
        v5p = h2{(_Float16)s[10*64], (_Float16)s[11*64]};
        v6p = h2{(_Float16)s[12*64], (_Float16)s[13*64]};
        v7p = h2{(_Float16)s[14*64], (_Float16)s[15*64]};
    }

    const float Qv  = softplus_f(qraw[d2]);
    const float b2v = dynb2[d2];
    float vreg = v0[d2];
    if (tid < 64) lm[0][tid] = (_Float16)m0[tid];

    // prefetch ring, distance 2: (hpre, al1, al2) for t and t+1
    float hp0 = preU[((size_t)0*NB + n)*256 + hh];
    float a10 = alpha[((size_t)0*NB + n)*128 + d2];
    float a20 = alpha[((size_t)0*NB + n)*128 + 64 + d2];
    float hp1 = preU[((size_t)1*NB + n)*256 + hh];
    float a11 = alpha[((size_t)1*NB + n)*128 + d2];
    float a21 = alpha[((size_t)1*NB + n)*128 + 64 + d2];
    __syncthreads();

    int cur = 0;
    for (int t = 0; t < T_LEN; ++t) {
        float hpN = 0.f, a1N = 0.f, a2N = 0.f;
        if (t + 2 < T_LEN) {
            hpN = preU[((size_t)(t+2)*NB + n)*256 + hh];
            a1N = alpha[((size_t)(t+2)*NB + n)*128 + d2];
            a2N = alpha[((size_t)(t+2)*NB + n)*128 + 64 + d2];
        }

        // L1: partial dot over m slice (f16), pair+quad shuffle reduce
        {
            const _Float16* mb = &lm[cur][pp*16];
            float4 r0 = *(const float4*)mb;
            float4 r1 = *(const float4*)(mb + 8);
            float c0 = dot2(f2h2(r0.x), u0, 0.f);
            float c1 = dot2(f2h2(r0.y), u1, 0.f);
            float c2 = dot2(f2h2(r0.z), u2, 0.f);
            float c3 = dot2(f2h2(r0.w), u3, 0.f);
            c0 = dot2(f2h2(r1.x), u4, c0);
            c1 = dot2(f2h2(r1.y), u5, c1);
            c2 = dot2(f2h2(r1.z), u6, c2);
            c3 = dot2(f2h2(r1.w), u7, c3);
            float acc = (c0+c1) + (c2+c3);
            acc += __shfl_xor(acc, 1);
            acc += __shfl_xor(acc, 2);
            if (pp == 0) lhid[LHF(hh)] = (_Float16)fast_tanh(hp0 + acc);
        }
        bar_sync();

        // L2: partial dot over hid slice (f16), 4-level butterfly -> full sum
        {
            const _Float16* hb = &lhid[LHF(qq*16)];
            float4 r0 = *(const float4*)hb;
            float4 r1 = *(const float4*)(hb + 8);
            float c0 = dot2(f2h2(r0.x), v0p, 0.f);
            float c1 = dot2(f2h2(r0.y), v1p, 0.f);
            float c2 = dot2(f2h2(r0.z), v2p, 0.f);
            float c3 = dot2(f2h2(r0.w), v3p, 0.f);
            c0 = dot2(f2h2(r1.x), v4p, c0);
            c1 = dot2(f2h2(r1.y), v5p, c1);
            c2 = dot2(f2h2(r1.z), v6p, c2);
            c3 = dot2(f2h2(r1.w), v7p, c3);
            float acc = (c0+c1) + (c2+c3);
            acc += __shfl_xor(acc, 1);
            acc += __shfl_xor(acc, 2);
            acc += __shfl_xor(acc, 4);
            acc += __shfl_xor(acc, 8);

            float m_p = acc + b2v;
            float v_p = vreg + Qv;
            float rvp = __builtin_amdgcn_rcpf(v_p);
            float e1 = m_p * rvp + a10;
            float e2 = a20 - 0.5f * rvp;
            float v_s = -0.5f * __builtin_amdgcn_rcpf(e2);
            float m_s = v_s * e1;
            vreg = v_s;
            if (qq == 0) lm[cur ^ 1][d2] = (_Float16)m_s;

            if (qq < 4) {
                size_t ob = ((size_t)n * T_LEN + t) * 256;
                float val = (qq == 0) ? m_s : (qq == 1) ? v_s : (qq == 2) ? m_p : v_p;
                out[ob + (size_t)qq*64 + d2] = val;
            }
        }
        bar_sync();
        cur ^= 1;
        hp0 = hp1; a10 = a11; a20 = a21;
        hp1 = hpN; a11 = a1N; a21 = a2N;
    }
}

// -------------------------------------------------------------------------
extern "C" void kernel_launch(void* const* d_in, const int* in_sizes, int n_in,
                              void* d_out, int out_size, void* d_ws, size_t ws_size,
                              hipStream_t stream) {
    const float* y      = (const float*)d_in[1];
    const float* u      = (const float*)d_in[2];
    const float* enc_w1 = (const float*)d_in[3];
    const float* enc_b1 = (const float*)d_in[4];
    const float* enc_w2 = (const float*)d_in[5];
    const float* enc_b2 = (const float*)d_in[6];
    const float* bw_wa  = (const float*)d_in[7];
    const float* bw_wh  = (const float*)d_in[8];
    const float* bw_b   = (const float*)d_in[9];
    const float* bw_wo  = (const float*)d_in[10];
    const float* bw_bo  = (const float*)d_in[11];
    const float* dyn_w1 = (const float*)d_in[12];
    const float* dyn_b1 = (const float*)d_in[13];
    const float* dyn_w2 = (const float*)d_in[14];
    const float* dyn_b2 = (const float*)d_in[15];
    const float* q_raw  = (const float*)d_in[16];
    const float* m0     = (const float*)d_in[17];
    const float* v0     = (const float*)d_in[18];
    float* out = (float*)d_out;

    float* ws = (float*)d_ws;
    float* apre  = ws;                  // [T*NB][128]
    float* hcell = ws + 4194304;        // [T*NB][128]
    float* alpha = ws;                  // aliases apre (apre dead after K2)
    float* preU  = ws + 2 * 4194304;    // [T*NB][256]

    k_encoder<<<4096, 256, 0, stream>>>(y, u, enc_w1, enc_b1, enc_w2, enc_b2,
                                        bw_wa, bw_b, dyn_w1, dyn_b1, apre, preU);
    k_bwscan<<<NB, 1024, 0, stream>>>(apre, bw_wh, hcell);
    k_alpha<<<4096, 256, 0, stream>>>(hcell, bw_wo, bw_bo, alpha);
    k_fwscan<<<NB, 1024, 0, stream>>>(alpha, preU, dyn_w1, dyn_w2, dyn_b2,
                                      q_raw, m0, v0, out);
}